// Round 5
// baseline (126.836 us; speedup 1.0000x reference)
//
#include <hip/hip_runtime.h>

#define SEQ 4096
#define DIM 1024
#define MD 64
#define TOPK 16
#define WPB 2                 // waves per block
#define RPW 4                 // rows per wave (4 independent chains)
#define RPB (WPB * RPW)       // 8 rows per block, 32 KB LDS

typedef float nfloat4 __attribute__((ext_vector_type(4)));  // native vec for nt store

// R10: quad-row element-major LDS. y[d] for 4 rows packed in one 16B unit ->
// phase-2 gather is 16 x ds_read_b128 (all 4 rows per instruction; was 64 x
// ds_read_b32 per 4 rows). One ballot search + perm pass serves 4 rows.
// XOR swizzle U = u ^ ((u>>3)&7) on the 16B unit index: the element-major
// layout would otherwise put the linear phase-1/4 accesses (u = 4*lane + i)
// on a 2-lane bank period; the swizzle spreads each i over all 8 bank groups
// (lanes L=2a+b -> group (4b+i)^(a&7), full cover). Same swizzle at all 3
// access sites. Occupancy 10 waves/CU x 4 chains = latency capacity of R6's
// 20 x 2, with ~40% fewer DS instructions per row and 2x ballot amortization.
__device__ __forceinline__ int swzU(int u) { return u ^ ((u >> 3) & 7); }

__global__ __launch_bounds__(WPB * 64) void csa_kernel(
    const float* __restrict__ x,
    const float* __restrict__ gates,
    const float* __restrict__ alpha,
    const float* __restrict__ tau,
    const float* __restrict__ signs,
    const int*   __restrict__ perm,
    const int*   __restrict__ inv_perm,
    const int*   __restrict__ target_idx,
    float*       __restrict__ out)
{
    __shared__ float lds[RPB * DIM];                  // 32 KB

    const int lane = threadIdx.x & 63;
    const int wv   = threadIdx.x >> 6;
    const int r0   = (blockIdx.x * WPB + wv) * RPW;   // first of 4 rows
    const int b    = r0 >> 12;                        // SEQ = 4096; quad shares b

    float4* Lw = (float4*)(lds + wv * (RPW * DIM));   // this wave's 16 KB, 16B units

    // ---- Phase 1: coalesced loads; transpose 4 rows into element-major LDS.
    // Rows are wave-private: no barrier, only lgkmcnt (compiler-inserted).
    #pragma unroll
    for (int c = 0; c < 4; ++c) {
        const float4 sg = ((const float4*)signs)[c * 64 + lane];
        float4 a[RPW];
        #pragma unroll
        for (int r = 0; r < RPW; ++r) {
            const float4 xv = ((const float4*)(x + (size_t)(r0 + r) * DIM))[c * 64 + lane];
            a[r].x = xv.x * sg.x; a[r].y = xv.y * sg.y;
            a[r].z = xv.z * sg.z; a[r].w = xv.w * sg.w;
        }
        const int d0 = c * 256 + 4 * lane;
        float4 u0, u1, u2, u3;                        // element-major units
        u0.x = a[0].x; u0.y = a[1].x; u0.z = a[2].x; u0.w = a[3].x;
        u1.x = a[0].y; u1.y = a[1].y; u1.z = a[2].y; u1.w = a[3].y;
        u2.x = a[0].z; u2.y = a[1].z; u2.z = a[2].z; u2.w = a[3].z;
        u3.x = a[0].w; u3.y = a[1].w; u3.z = a[2].w; u3.w = a[3].w;
        Lw[swzU(d0 + 0)] = u0;
        Lw[swzU(d0 + 1)] = u1;
        Lw[swzU(d0 + 2)] = u2;
        Lw[swzU(d0 + 3)] = u3;
    }

    // ---- Phase 2: fold 1024 -> 64 bins; ONE b128 gather feeds all 4 rows.
    // Element perm[lane + 64k] has bin == lane.
    float s0 = 0.f, s1 = 0.f, s2 = 0.f, s3 = 0.f;
    #pragma unroll
    for (int k = 0; k < 16; ++k) {
        const int p = perm[lane + 64 * k];            // coalesced, L1-hot 4 KB
        const float4 q = Lw[swzU(p)];                 // ds_read_b128, random
        s0 += q.x; s1 += q.y; s2 += q.z; s3 += q.w;
    }

    // ---- Phase 3a: 64-pt Hadamard, 4 chains interleaved
    float v0 = s0, v1 = s1, v2 = s2, v3 = s3;
    #pragma unroll
    for (int bit = 1; bit < MD; bit <<= 1) {
        const float o0 = __shfl_xor(v0, bit, 64);
        const float o1 = __shfl_xor(v1, bit, 64);
        const float o2 = __shfl_xor(v2, bit, 64);
        const float o3 = __shfl_xor(v3, bit, 64);
        v0 = (lane & bit) ? (o0 - v0) : (v0 + o0);
        v1 = (lane & bit) ? (o1 - v1) : (v1 + o1);
        v2 = (lane & bit) ? (o2 - v2) : (v2 + o2);
        v3 = (lane & bit) ? (o3 - v3) : (v3 + o3);
    }

    const int   ti   = target_idx[0];                 // NT == 1
    const float gate = gates[(b + ti) * MD + lane];
    const float tauv = fabsf(tau[b + ti]);
    const float al   = alpha[b + ti];

    const float g0 = gate * v0 * 0.03125f;            // 1024^-0.5
    const float g1 = gate * v1 * 0.03125f;
    const float g2 = gate * v2 * 0.03125f;
    const float g3 = gate * v3 * 0.03125f;
    const float ag0 = fabsf(g0), ag1 = fabsf(g1), ag2 = fabsf(g2), ag3 = fabsf(g3);

    // ---- Phase 3b: exact top-16 via bitwise binary search (4 chains);
    // ties -> lowest lane (matches jax.lax.top_k)
    const unsigned ka0 = __float_as_uint(ag0);
    const unsigned ka1 = __float_as_uint(ag1);
    const unsigned ka2 = __float_as_uint(ag2);
    const unsigned ka3 = __float_as_uint(ag3);
    unsigned T0 = 0u, T1 = 0u, T2 = 0u, T3 = 0u;
    #pragma unroll
    for (int bit = 30; bit >= 0; --bit) {
        const unsigned c0 = T0 | (1u << bit);
        const unsigned c1 = T1 | (1u << bit);
        const unsigned c2 = T2 | (1u << bit);
        const unsigned c3 = T3 | (1u << bit);
        if (__popcll(__ballot(ka0 >= c0)) >= TOPK) T0 = c0;
        if (__popcll(__ballot(ka1 >= c1)) >= TOPK) T1 = c1;
        if (__popcll(__ballot(ka2 >= c2)) >= TOPK) T2 = c2;
        if (__popcll(__ballot(ka3 >= c3)) >= TOPK) T3 = c3;
    }
    const unsigned long long lm = (1ull << lane) - 1ull;
    const int ngt0 = __popcll(__ballot(ka0 > T0));
    const int ngt1 = __popcll(__ballot(ka1 > T1));
    const int ngt2 = __popcll(__ballot(ka2 > T2));
    const int ngt3 = __popcll(__ballot(ka3 > T3));
    const int er0 = __popcll(__ballot(ka0 == T0) & lm);
    const int er1 = __popcll(__ballot(ka1 == T1) & lm);
    const int er2 = __popcll(__ballot(ka2 == T2) & lm);
    const int er3 = __popcll(__ballot(ka3 == T3) & lm);
    const bool k0 = (ka0 > T0) || ((ka0 == T0) && (er0 < TOPK - ngt0));
    const bool k1 = (ka1 > T1) || ((ka1 == T1) && (er1 < TOPK - ngt1));
    const bool k2 = (ka2 > T2) || ((ka2 == T2) && (er2 < TOPK - ngt2));
    const bool k3 = (ka3 > T3) || ((ka3 == T3) && (er3 < TOPK - ngt3));

    float zs0 = (k0 && ag0 >= tauv) ? al * g0 : 0.f;
    float zs1 = (k1 && ag1 >= tauv) ? al * g1 : 0.f;
    float zs2 = (k2 && ag2 >= tauv) ? al * g2 : 0.f;
    float zs3 = (k3 && ag3 >= tauv) ? al * g3 : 0.f;

    // ---- Phase 3c: second 64-pt Hadamard, 4 chains
    #pragma unroll
    for (int bit = 1; bit < MD; bit <<= 1) {
        const float o0 = __shfl_xor(zs0, bit, 64);
        const float o1 = __shfl_xor(zs1, bit, 64);
        const float o2 = __shfl_xor(zs2, bit, 64);
        const float o3 = __shfl_xor(zs3, bit, 64);
        zs0 = (lane & bit) ? (o0 - zs0) : (zs0 + o0);
        zs1 = (lane & bit) ? (o1 - zs1) : (zs1 + o1);
        zs2 = (lane & bit) ? (o2 - zs2) : (zs2 + o2);
        zs3 = (lane & bit) ? (o3 - zs3) : (zs3 + o3);
    }
    const float w0 = zs0 * 0.03125f;                  // lane L holds w_r[bin == L]
    const float w1 = zs1 * 0.03125f;
    const float w2 = zs2 * 0.03125f;
    const float w3 = zs3 * 0.03125f;

    // ---- Phase 4: out_r = signs * ( y_r (element-major readback) + w_r[bin] )
    #pragma unroll
    for (int c = 0; c < 4; ++c) {
        const int4   ip = ((const int4*)inv_perm)[c * 64 + lane];
        const float4 sg = ((const float4*)signs)[c * 64 + lane];
        const int d0 = c * 256 + 4 * lane;
        const float4 t0 = Lw[swzU(d0 + 0)];           // (y0..y3)[d0+0]
        const float4 t1 = Lw[swzU(d0 + 1)];
        const float4 t2 = Lw[swzU(d0 + 2)];
        const float4 t3 = Lw[swzU(d0 + 3)];
        const int b0 = ip.x & 63, b1 = ip.y & 63, b2 = ip.z & 63, b3 = ip.w & 63;

        nfloat4 o0, o1, o2, o3;                       // per ROW outputs
        o0.x = sg.x * (t0.x + __shfl(w0, b0, 64));
        o0.y = sg.y * (t1.x + __shfl(w0, b1, 64));
        o0.z = sg.z * (t2.x + __shfl(w0, b2, 64));
        o0.w = sg.w * (t3.x + __shfl(w0, b3, 64));
        o1.x = sg.x * (t0.y + __shfl(w1, b0, 64));
        o1.y = sg.y * (t1.y + __shfl(w1, b1, 64));
        o1.z = sg.z * (t2.y + __shfl(w1, b2, 64));
        o1.w = sg.w * (t3.y + __shfl(w1, b3, 64));
        o2.x = sg.x * (t0.z + __shfl(w2, b0, 64));
        o2.y = sg.y * (t1.z + __shfl(w2, b1, 64));
        o2.z = sg.z * (t2.z + __shfl(w2, b2, 64));
        o2.w = sg.w * (t3.z + __shfl(w2, b3, 64));
        o3.x = sg.x * (t0.w + __shfl(w3, b0, 64));
        o3.y = sg.y * (t1.w + __shfl(w3, b1, 64));
        o3.z = sg.z * (t2.w + __shfl(w3, b2, 64));
        o3.w = sg.w * (t3.w + __shfl(w3, b3, 64));

        __builtin_nontemporal_store(o0, &((nfloat4*)(out + (size_t)(r0 + 0) * DIM))[c * 64 + lane]);
        __builtin_nontemporal_store(o1, &((nfloat4*)(out + (size_t)(r0 + 1) * DIM))[c * 64 + lane]);
        __builtin_nontemporal_store(o2, &((nfloat4*)(out + (size_t)(r0 + 2) * DIM))[c * 64 + lane]);
        __builtin_nontemporal_store(o3, &((nfloat4*)(out + (size_t)(r0 + 3) * DIM))[c * 64 + lane]);
    }
}

extern "C" void kernel_launch(void* const* d_in, const int* in_sizes, int n_in,
                              void* d_out, int out_size, void* d_ws, size_t ws_size,
                              hipStream_t stream) {
    const float* x        = (const float*)d_in[0];
    const float* gates    = (const float*)d_in[1];
    const float* alpha    = (const float*)d_in[2];
    const float* tau      = (const float*)d_in[3];
    const float* signs    = (const float*)d_in[4];
    const int*   perm     = (const int*)d_in[5];
    const int*   inv_perm = (const int*)d_in[6];
    const int*   tgt      = (const int*)d_in[7];
    float*       out      = (float*)d_out;

    const int rows = 4 * SEQ;                         // BSZ * SEQ = 16384
    csa_kernel<<<rows / RPB, WPB * 64, 0, stream>>>(x, gates, alpha, tau, signs,
                                                    perm, inv_perm, tgt, out);
}

// Round 6
// 125.962 us; speedup vs baseline: 1.0069x; 1.0069x over previous
//
#include <hip/hip_runtime.h>

#define SEQ 4096
#define DIM 1024
#define MD 64
#define TOPK 16
#define WPB 2                 // waves per block
#define RPW 2                 // rows per wave (ILP: two independent chains)
#define RPB (WPB * RPW)       // 4 rows per block-iteration, 16 KB LDS
#define GRID 2048             // blocks; 8 resident/CU (LDS cap is 10)
#define ITERS 2               // GRID * RPB * ITERS = 16384 rows

typedef float nfloat4 __attribute__((ext_vector_type(4)));  // native vec for nt store

// R11 = R9 + cross-iteration software pipeline (persistent-ish grid-stride).
// R10's counters showed the kernel is latency-bound with nothing saturated
// (HBM 29%, VALU 11%, DS ~25%, occ 5.6 waves/CU): waves run load-burst ->
// serial chain -> store-burst in phase, exposing HBM latency. Fix: each block
// handles 2 row-quads; the NEXT quad's x loads are issued into registers
// right after the current quad's LDS staging, so they fly during the current
// chain (gather + 2x Hadamard + ballot top-k). GRID=2048 keeps 8 blocks/CU
// resident from t=0; __launch_bounds__(128,4) caps VGPR at 128 so the 8
// blocks always fit. perm gathers (pk[16]) and signs (sg[4]) are hoisted as
// loop invariants off the critical path.
__global__ __launch_bounds__(WPB * 64, 4) void csa_kernel(
    const float* __restrict__ x,
    const float* __restrict__ gates,
    const float* __restrict__ alpha,
    const float* __restrict__ tau,
    const float* __restrict__ signs,
    const int*   __restrict__ perm,
    const int*   __restrict__ inv_perm,
    const int*   __restrict__ target_idx,
    float*       __restrict__ out)
{
    __shared__ float y[RPB][DIM];

    const int lane = threadIdx.x & 63;
    const int wv   = threadIdx.x >> 6;

    float* y0 = y[wv * RPW + 0];
    float* y1 = y[wv * RPW + 1];

    // ---- Loop-invariant state (hoisted): perm gather indices, signs, target
    int pk[16];
    #pragma unroll
    for (int k = 0; k < 16; ++k) pk[k] = perm[lane + 64 * k];   // L1-hot 4 KB
    float4 sg[4];
    #pragma unroll
    for (int c = 0; c < 4; ++c) sg[c] = ((const float4*)signs)[c * 64 + lane];
    const int ti = target_idx[0];                               // NT == 1

    // ---- Prologue: prefetch iteration 0's two rows into registers
    int r0 = (blockIdx.x * WPB + wv) * RPW;
    float4 xa[4], xb[4];
    #pragma unroll
    for (int c = 0; c < 4; ++c) {
        xa[c] = ((const float4*)(x + (size_t)(r0 + 0) * DIM))[c * 64 + lane];
        xb[c] = ((const float4*)(x + (size_t)(r0 + 1) * DIM))[c * 64 + lane];
    }

    #pragma unroll
    for (int t = 0; t < ITERS; ++t) {
        const int b = r0 >> 12;                   // SEQ = 4096; pair shares b

        // ---- Phase 1: consume prefetch; y = x*signs -> LDS (wave-private,
        // no barrier; DS ops are in-order per wave so reuse across t is safe)
        #pragma unroll
        for (int c = 0; c < 4; ++c) {
            float4 a, bq;
            a.x  = xa[c].x * sg[c].x; a.y  = xa[c].y * sg[c].y;
            a.z  = xa[c].z * sg[c].z; a.w  = xa[c].w * sg[c].w;
            bq.x = xb[c].x * sg[c].x; bq.y = xb[c].y * sg[c].y;
            bq.z = xb[c].z * sg[c].z; bq.w = xb[c].w * sg[c].w;
            ((float4*)y0)[c * 64 + lane] = a;
            ((float4*)y1)[c * 64 + lane] = bq;
        }

        // ---- Issue NEXT iteration's global loads now; they overlap the
        // whole chain below (~2-3k cycles >> HBM latency)
        const int r0n = r0 + GRID * RPB;
        if (t + 1 < ITERS) {
            #pragma unroll
            for (int c = 0; c < 4; ++c) {
                xa[c] = ((const float4*)(x + (size_t)(r0n + 0) * DIM))[c * 64 + lane];
                xb[c] = ((const float4*)(x + (size_t)(r0n + 1) * DIM))[c * 64 + lane];
            }
        }

        // ---- Phase 2: fold 1024 -> 64 bins (element pk[k] has bin == lane)
        float s0 = 0.f, s1 = 0.f;
        #pragma unroll
        for (int k = 0; k < 16; ++k) {
            s0 += y0[pk[k]];                      // random ds_read_b32
            s1 += y1[pk[k]];
        }

        // ---- Phase 3a: 64-pt Hadamard, both rows interleaved
        float v0 = s0, v1 = s1;
        #pragma unroll
        for (int bit = 1; bit < MD; bit <<= 1) {
            const float o0 = __shfl_xor(v0, bit, 64);
            const float o1 = __shfl_xor(v1, bit, 64);
            v0 = (lane & bit) ? (o0 - v0) : (v0 + o0);
            v1 = (lane & bit) ? (o1 - v1) : (v1 + o1);
        }

        const float gate = gates[(b + ti) * MD + lane];
        const float tauv = fabsf(tau[b + ti]);
        const float al   = alpha[b + ti];

        const float g0 = gate * v0 * 0.03125f;    // 1024^-0.5
        const float g1 = gate * v1 * 0.03125f;
        const float ag0 = fabsf(g0), ag1 = fabsf(g1);

        // ---- Phase 3b: exact top-16 via bitwise binary search (2 chains);
        // ties -> lowest lane (matches jax.lax.top_k)
        const unsigned ka0 = __float_as_uint(ag0);
        const unsigned ka1 = __float_as_uint(ag1);
        unsigned T0 = 0u, T1 = 0u;
        #pragma unroll
        for (int bit = 30; bit >= 0; --bit) {
            const unsigned c0 = T0 | (1u << bit);
            const unsigned c1 = T1 | (1u << bit);
            if (__popcll(__ballot(ka0 >= c0)) >= TOPK) T0 = c0;
            if (__popcll(__ballot(ka1 >= c1)) >= TOPK) T1 = c1;
        }
        const int ngt0 = __popcll(__ballot(ka0 > T0));
        const int ngt1 = __popcll(__ballot(ka1 > T1));
        const unsigned long long lm = (1ull << lane) - 1ull;
        const int er0 = __popcll(__ballot(ka0 == T0) & lm);
        const int er1 = __popcll(__ballot(ka1 == T1) & lm);
        const bool k0 = (ka0 > T0) || ((ka0 == T0) && (er0 < TOPK - ngt0));
        const bool k1 = (ka1 > T1) || ((ka1 == T1) && (er1 < TOPK - ngt1));

        float zs0 = (k0 && ag0 >= tauv) ? al * g0 : 0.f;
        float zs1 = (k1 && ag1 >= tauv) ? al * g1 : 0.f;

        // ---- Phase 3c: second 64-pt Hadamard, interleaved
        #pragma unroll
        for (int bit = 1; bit < MD; bit <<= 1) {
            const float o0 = __shfl_xor(zs0, bit, 64);
            const float o1 = __shfl_xor(zs1, bit, 64);
            zs0 = (lane & bit) ? (o0 - zs0) : (zs0 + o0);
            zs1 = (lane & bit) ? (o1 - zs1) : (zs1 + o1);
        }
        const float w0 = zs0 * 0.03125f;          // lane L holds w[bin == L]
        const float w1 = zs1 * 0.03125f;

        // ---- Phase 4: out = signs * ( y (linear LDS readback) + bpermute(w) )
        nfloat4* orow0 = (nfloat4*)(out + (size_t)(r0 + 0) * DIM);
        nfloat4* orow1 = (nfloat4*)(out + (size_t)(r0 + 1) * DIM);
        #pragma unroll
        for (int c = 0; c < 4; ++c) {
            const int4   ip = ((const int4*)inv_perm)[c * 64 + lane];  // L1-hot
            const float4 t0 = ((const float4*)y0)[c * 64 + lane];      // b128
            const float4 t1 = ((const float4*)y1)[c * 64 + lane];
            const float wx0 = __shfl(w0, ip.x & 63, 64);
            const float wy0 = __shfl(w0, ip.y & 63, 64);
            const float wz0 = __shfl(w0, ip.z & 63, 64);
            const float ww0 = __shfl(w0, ip.w & 63, 64);
            const float wx1 = __shfl(w1, ip.x & 63, 64);
            const float wy1 = __shfl(w1, ip.y & 63, 64);
            const float wz1 = __shfl(w1, ip.z & 63, 64);
            const float ww1 = __shfl(w1, ip.w & 63, 64);
            nfloat4 o0, o1;
            o0.x = sg[c].x * (t0.x + wx0);
            o0.y = sg[c].y * (t0.y + wy0);
            o0.z = sg[c].z * (t0.z + wz0);
            o0.w = sg[c].w * (t0.w + ww0);
            o1.x = sg[c].x * (t1.x + wx1);
            o1.y = sg[c].y * (t1.y + wy1);
            o1.z = sg[c].z * (t1.z + wz1);
            o1.w = sg[c].w * (t1.w + ww1);
            __builtin_nontemporal_store(o0, &orow0[c * 64 + lane]);
            __builtin_nontemporal_store(o1, &orow1[c * 64 + lane]);
        }

        r0 = r0n;
    }
}

extern "C" void kernel_launch(void* const* d_in, const int* in_sizes, int n_in,
                              void* d_out, int out_size, void* d_ws, size_t ws_size,
                              hipStream_t stream) {
    const float* x        = (const float*)d_in[0];
    const float* gates    = (const float*)d_in[1];
    const float* alpha    = (const float*)d_in[2];
    const float* tau      = (const float*)d_in[3];
    const float* signs    = (const float*)d_in[4];
    const int*   perm     = (const int*)d_in[5];
    const int*   inv_perm = (const int*)d_in[6];
    const int*   tgt      = (const int*)d_in[7];
    float*       out      = (float*)d_out;

    csa_kernel<<<GRID, WPB * 64, 0, stream>>>(x, gates, alpha, tau, signs,
                                              perm, inv_perm, tgt, out);
}